// Round 1
// baseline (360.940 us; speedup 1.0000x reference)
//
#include <hip/hip_runtime.h>
#include <hip/hip_bf16.h>

// Problem constants: B,L,M,D,K,STRIDE = 32,32768,32,128,16,8
#define Bn 32
#define Ln 32768
#define Mn 32
#define Dn 128
#define Pn 4095            // (L - K)/STRIDE + 1
#define KKn 512            // M*K  (GEMM reduction dim)

typedef short  bf16x8 __attribute__((ext_vector_type(8)));  // 8 bf16 = 4 VGPRs
typedef float  f32x4  __attribute__((ext_vector_type(4)));

union BU { bf16x8 v; unsigned short u[8]; };

static __device__ __forceinline__ unsigned short f2bf(float f) {
  __hip_bfloat16 h = __float2bfloat16(f);
  return *reinterpret_cast<unsigned short*>(&h);
}

static __device__ __forceinline__ int swz(int g) {
  // xor swizzle on 16-B granules: kills the 512-B p-stride bank conflict
  return (g & ~7) | ((g & 7) ^ ((g >> 5) & 7));
}

// ---------------------------------------------------------------------------
// Prep: conv_w (D,M,K) fp32 -> fragment-ready swizzled bf16 in d_ws.
// kk = k*32 + m; B-frag lane d=lane&15, kk=t*32+quad*8+j
//   -> wswz[((kk>>3)*128 + d)*8 + (kk&7)]  (one 16-B load per fragment)
// ---------------------------------------------------------------------------
__global__ __launch_bounds__(256) void prep_w_kernel(const float* __restrict__ w,
                                                     unsigned short* __restrict__ wswz) {
  int idx = blockIdx.x * 256 + threadIdx.x;   // 0..65535
  int j = idx & 7;
  int d = (idx >> 3) & 127;
  int g = idx >> 10;
  int kk = g * 8 + j;
  int k = kk >> 5;
  int m = kk & 31;
  wswz[idx] = f2bf(w[(d << 9) + (m << 4) + k]);   // w[d][m][k]
}

// ---------------------------------------------------------------------------
// Main: each block owns a PAIR of 64-patch tiles = 128 patches, processed as
// 4 pipelined half-slabs of 32 patches (264 rows = 1056 granules each),
// double-buffered in LDS. Grid = 32 x 32 = 1024 blocks = one full resident
// generation at 4 blocks/CU. Per half: issue next-half loads -> K-loop ->
// epilogue -> drain+convert+ds_write -> barrier (T14 issue-early/write-late).
// B-fragment ring is depth-4, circular mod 16 -> stays warm across halves.
// ---------------------------------------------------------------------------
#define GHALF 1056            // granules per half (264 rows x 4)
#define BUFS  (GHALF * 8)     // shorts per half buffer

__global__ __launch_bounds__(256, 4) void gemm_pe_kernel(
    const float* __restrict__ x,          // (B, L, M) fp32
    const float* __restrict__ ts,         // (B, L)    fp32, sorted along L
    const unsigned short* __restrict__ wswz,
    const float* __restrict__ bias,       // (D,)
    float* __restrict__ out) {            // (B, P, D) fp32

  __shared__ unsigned short xs[2][BUFS];  // 2 x 16,896 B = 33,792 B
  __shared__ float tsl[128];              // medians for this block's 128 patches

  const int b    = blockIdx.y;
  const int pair = blockIdx.x;            // 0..31, patches pair*128 .. +127
  const int tid  = threadIdx.x;
  const int lane = tid & 63;
  const int wv   = tid >> 6;
  const int mrow = lane & 15;
  const int quad = lane >> 4;

  const float* xpair = x + (size_t)b * Ln * Mn + (size_t)pair * 1024 * Mn;

  // ---------------- prologue: issue half-0 loads + ts + B-ring -------------
  float4 fr[5][2];
  {
    const float4* hsrc = reinterpret_cast<const float4*>(xpair);
    #pragma unroll
    for (int i = 0; i < 4; ++i) {
      const float4* src = hsrc + (size_t)(i * 256 + tid) * 2;
      fr[i][0] = src[0];
      fr[i][1] = src[1];
    }
    fr[4][0] = make_float4(0.f, 0.f, 0.f, 0.f); fr[4][1] = fr[4][0];
    if (tid < 32) {                       // rows 256..263, always in-bounds here
      const float4* src = hsrc + (size_t)(1024 + tid) * 2;
      fr[4][0] = src[0];
      fr[4][1] = src[1];
    }
  }
  // ts medians for all 128 patches (sorted ts -> median of 16-window = elem 7)
  float tsv = 0.f;
  if (tid < 128) tsv = ts[(size_t)b * Ln + (size_t)(pair * 128 + tid) * 8 + 7];

  // B-frag ring: depth 4, circular mod 16 (16 % 4 == 0 keeps phase across halves)
  const unsigned short* bbase = wswz + (((quad << 7) + (wv << 5) + mrow) << 3);
  bf16x8 bp[4][2];
  #pragma unroll
  for (int j = 0; j < 4; ++j) {
    bp[j][0] = *reinterpret_cast<const bf16x8*>(bbase + j * 4096);
    bp[j][1] = *reinterpret_cast<const bf16x8*>(bbase + 128 + j * 4096);
  }

  // epilogue scalars (VALU, free under load shadow)
  const int d0 = wv * 32 + mrow;
  const float NEG_C = -0.14391156831212810f;            // -ln(10000)/64
  const float div0 = __expf(NEG_C * (float)(d0 >> 1));
  const float div1 = __expf(NEG_C * (float)((d0 + 16) >> 1));
  const float phs  = (d0 & 1) ? 1.5707963267948966f : 0.0f;
  const float bias0 = bias[d0];
  const float bias1 = bias[d0 + 16];

  __builtin_amdgcn_sched_barrier(0);   // keep all prologue loads issued first

  // convert + write half 0
  #pragma unroll
  for (int i = 0; i < 4; ++i) {
    int gl = i * 256 + tid;
    BU bu;
    bu.u[0] = f2bf(fr[i][0].x); bu.u[1] = f2bf(fr[i][0].y);
    bu.u[2] = f2bf(fr[i][0].z); bu.u[3] = f2bf(fr[i][0].w);
    bu.u[4] = f2bf(fr[i][1].x); bu.u[5] = f2bf(fr[i][1].y);
    bu.u[6] = f2bf(fr[i][1].z); bu.u[7] = f2bf(fr[i][1].w);
    *reinterpret_cast<bf16x8*>(&xs[0][swz(gl) * 8]) = bu.v;
  }
  if (tid < 32) {
    BU bu;
    bu.u[0] = f2bf(fr[4][0].x); bu.u[1] = f2bf(fr[4][0].y);
    bu.u[2] = f2bf(fr[4][0].z); bu.u[3] = f2bf(fr[4][0].w);
    bu.u[4] = f2bf(fr[4][1].x); bu.u[5] = f2bf(fr[4][1].y);
    bu.u[6] = f2bf(fr[4][1].z); bu.u[7] = f2bf(fr[4][1].w);
    *reinterpret_cast<bf16x8*>(&xs[0][swz(1024 + tid) * 8]) = bu.v;
  }
  if (tid < 128) tsl[tid] = tsv;
  __syncthreads();

  const int agA = (mrow * 32) + quad;          // pt 0: local patches 0..15
  const int agB = ((16 + mrow) * 32) + quad;   // pt 1: local patches 16..31

  #pragma unroll 1
  for (int h = 0; h < 4; ++h) {
    // ---- issue next-half global loads; they land under this half's K-loop --
    if (h < 3) {
      const float4* hsrc = reinterpret_cast<const float4*>(xpair + (size_t)(h + 1) * 8192);
      #pragma unroll
      for (int i = 0; i < 4; ++i) {
        const float4* src = hsrc + (size_t)(i * 256 + tid) * 2;
        fr[i][0] = src[0];
        fr[i][1] = src[1];
      }
      fr[4][0] = make_float4(0.f, 0.f, 0.f, 0.f); fr[4][1] = fr[4][0];
      // tail rows OOB only for pair==31, h+1==3 (rows 32768..32775)
      if (tid < 32 && (pair * 1024 + (h + 1) * 256 + 256) < Ln) {
        const float4* src = hsrc + (size_t)(1024 + tid) * 2;
        fr[4][0] = src[0];
        fr[4][1] = src[1];
      }
    }
    __builtin_amdgcn_sched_barrier(0);   // pin stage-issue above the K-loop

    // ---- K-loop: 16 steps of K=32 over buf h&1 ----------------------------
    const unsigned short* xb = &xs[h & 1][0];
    f32x4 acc[2][2] = {};
    #pragma unroll
    for (int t = 0; t < 16; ++t) {
      bf16x8 a0 = *reinterpret_cast<const bf16x8*>(&xb[swz(agA + t * 4) * 8]);
      bf16x8 a1 = *reinterpret_cast<const bf16x8*>(&xb[swz(agB + t * 4) * 8]);
      const int cur = t & 3;
      bf16x8 bc0 = bp[cur][0], bc1 = bp[cur][1];
      bp[cur][0] = *reinterpret_cast<const bf16x8*>(bbase + ((t + 4) & 15) * 4096);
      bp[cur][1] = *reinterpret_cast<const bf16x8*>(bbase + 128 + ((t + 4) & 15) * 4096);
      acc[0][0] = __builtin_amdgcn_mfma_f32_16x16x32_bf16(a0, bc0, acc[0][0], 0, 0, 0);
      acc[0][1] = __builtin_amdgcn_mfma_f32_16x16x32_bf16(a0, bc1, acc[0][1], 0, 0, 0);
      acc[1][0] = __builtin_amdgcn_mfma_f32_16x16x32_bf16(a1, bc0, acc[1][0], 0, 0, 0);
      acc[1][1] = __builtin_amdgcn_mfma_f32_16x16x32_bf16(a1, bc1, acc[1][1], 0, 0, 0);
    }

    // ---- epilogue: + bias + PE.  C/D: col=lane&15, row=quad*4+reg ---------
    #pragma unroll
    for (int pt = 0; pt < 2; ++pt) {
      const int plb = pt * 16 + quad * 4;
      f32x4 med4 = *reinterpret_cast<const f32x4*>(&tsl[h * 32 + plb]);
      const int pg = pair * 128 + h * 32 + plb;
      float* obase = out + ((size_t)b * Pn + pg) * Dn + d0;
      #pragma unroll
      for (int reg = 0; reg < 4; ++reg) {
        if (pg + reg < Pn) {
          float m = med4[reg];
          float pe0 = __sinf(m * div0 + phs);
          float pe1 = __sinf(m * div1 + phs);
          obase[reg * Dn]      = acc[pt][0][reg] + bias0 + pe0;
          obase[reg * Dn + 16] = acc[pt][1][reg] + bias1 + pe1;
        }
      }
    }

    // ---- drain next-half loads (long since landed), convert, flip ---------
    if (h < 3) {
      unsigned short* xw = &xs[(h + 1) & 1][0];
      #pragma unroll
      for (int i = 0; i < 4; ++i) {
        int gl = i * 256 + tid;
        BU bu;
        bu.u[0] = f2bf(fr[i][0].x); bu.u[1] = f2bf(fr[i][0].y);
        bu.u[2] = f2bf(fr[i][0].z); bu.u[3] = f2bf(fr[i][0].w);
        bu.u[4] = f2bf(fr[i][1].x); bu.u[5] = f2bf(fr[i][1].y);
        bu.u[6] = f2bf(fr[i][1].z); bu.u[7] = f2bf(fr[i][1].w);
        *reinterpret_cast<bf16x8*>(&xw[swz(gl) * 8]) = bu.v;
      }
      if (tid < 32) {
        BU bu;
        bu.u[0] = f2bf(fr[4][0].x); bu.u[1] = f2bf(fr[4][0].y);
        bu.u[2] = f2bf(fr[4][0].z); bu.u[3] = f2bf(fr[4][0].w);
        bu.u[4] = f2bf(fr[4][1].x); bu.u[5] = f2bf(fr[4][1].y);
        bu.u[6] = f2bf(fr[4][1].z); bu.u[7] = f2bf(fr[4][1].w);
        *reinterpret_cast<bf16x8*>(&xw[swz(1024 + tid) * 8]) = bu.v;
      }
      __syncthreads();
    }
  }
}

extern "C" void kernel_launch(void* const* d_in, const int* in_sizes, int n_in,
                              void* d_out, int out_size, void* d_ws, size_t ws_size,
                              hipStream_t stream) {
  const float* x      = (const float*)d_in[0];   // (32, 32768, 32)
  const float* ts     = (const float*)d_in[1];   // (32, 32768)
  const float* conv_w = (const float*)d_in[2];   // (128, 32, 16)
  const float* conv_b = (const float*)d_in[3];   // (128,)
  float* out = (float*)d_out;
  unsigned short* wswz = (unsigned short*)d_ws;  // 512*128 bf16 = 128 KiB

  prep_w_kernel<<<256, 256, 0, stream>>>(conv_w, wswz);
  gemm_pe_kernel<<<dim3(32, Bn), 256, 0, stream>>>(x, ts, wswz, conv_b, out);
}